// Round 2
// baseline (465.636 us; speedup 1.0000x reference)
//
#include <hip/hip_runtime.h>
#include <hip/hip_bf16.h>

namespace {
constexpr int B = 4, N = 6, D = 41, FH = 16, FW = 44, C = 64;
constexpr int NX = 200, NY = 200;                 // NZ = 1
constexpr int NPRIME = B * N * D * FH * FW;       // 692736
constexpr long long ACC_ELEMS = (long long)B * NY * NX * C;  // 10,240,000
constexpr int PARAMS_PER_CAM = 24;                // iPR[9], pt[3], M[9], t[3]
constexpr int FLAG_IDX = B * N * PARAMS_PER_CAM;  // int flag at params[576]
}

// Load input element as fp32, whatever the storage dtype actually is.
__device__ __forceinline__ float ldin(const void* p, size_t idx, int fp32m) {
  return fp32m ? ((const float*)p)[idx]
               : __bfloat162float(((const __hip_bfloat16*)p)[idx]);
}

// f64 adjugate inverse -> f32 (used for post_rots; exact for identity).
__device__ inline void inv3x3_f64(const float a_[9], float o[9]) {
  double a[9];
  for (int k = 0; k < 9; ++k) a[k] = (double)a_[k];
  double c00 = a[4] * a[8] - a[5] * a[7];
  double c01 = a[5] * a[6] - a[3] * a[8];
  double c02 = a[3] * a[7] - a[4] * a[6];
  double det = a[0] * c00 + a[1] * c01 + a[2] * c02;
  double id = 1.0 / det;
  o[0] = (float)(c00 * id);
  o[1] = (float)((a[2] * a[7] - a[1] * a[8]) * id);
  o[2] = (float)((a[1] * a[5] - a[2] * a[4]) * id);
  o[3] = (float)(c01 * id);
  o[4] = (float)((a[0] * a[8] - a[2] * a[6]) * id);
  o[5] = (float)((a[2] * a[3] - a[0] * a[5]) * id);
  o[6] = (float)(c02 * id);
  o[7] = (float)((a[1] * a[6] - a[0] * a[7]) * id);
  o[8] = (float)((a[0] * a[4] - a[1] * a[3]) * id);
}

// One thread per (b,n). Builds iPR, post_trans, combine = rots @ inv(intrins),
// trans — replicating numpy fp32 semantics (LAPACK strti2 for the upper-
// triangular intrinsics; strict no-FMA fp32 matmul).
__global__ void setup_kernel(const void* rots, const void* trans,
                             const void* intr, const void* prots,
                             const void* ptrans, float* params) {
  int i = threadIdx.x;
  float probe = ((const float*)intr)[0];  // 500.0 if fp32; denormal if bf16
  int fp32m = (probe > 100.f && probe < 2000.f) ? 1 : 0;
  if (i == 0) ((int*)params)[FLAG_IDX] = fp32m;
  if (i >= B * N) return;
  float R[9], K[9], PR[9];
  for (int k = 0; k < 9; ++k) {
    R[k] = ldin(rots, (size_t)i * 9 + k, fp32m);
    K[k] = ldin(intr, (size_t)i * 9 + k, fp32m);
    PR[k] = ldin(prots, (size_t)i * 9 + k, fp32m);
  }
  float iPR[9];
  inv3x3_f64(PR, iPR);  // exact identity for this problem
  // LAPACK strti2 (upper, non-unit) on K = [[fx,0,cx],[0,fy,cy],[0,0,1]]
  float i00 = __fdiv_rn(1.f, K[0]);
  float i11 = __fdiv_rn(1.f, K[4]);
  float i22 = __fdiv_rn(1.f, K[8]);
  float i01 = __fmul_rn(-i11, __fmul_rn(i00, K[1]));  // K[1]=0 -> 0
  float x1 = __fmul_rn(i00, K[2]);
  x1 = __fadd_rn(x1, __fmul_rn(K[5], i01));
  float x2 = __fmul_rn(i11, K[5]);
  float i02 = __fmul_rn(-i22, x1);
  float i12 = __fmul_rn(-i22, x2);
  float iK[9] = {i00, i01, i02, 0.f, i11, i12, 0.f, 0.f, i22};
  float* o = params + i * PARAMS_PER_CAM;
  for (int k = 0; k < 9; ++k) o[k] = iPR[k];
  for (int k = 0; k < 3; ++k) o[9 + k] = ldin(ptrans, (size_t)i * 3 + k, fp32m);
  // combine = R @ iK, strict fp32 left-fold (numpy matmul order, no FMA)
  for (int r = 0; r < 3; ++r)
    for (int c2 = 0; c2 < 3; ++c2) {
      float s = __fmul_rn(R[r * 3 + 0], iK[0 * 3 + c2]);
      s = __fadd_rn(s, __fmul_rn(R[r * 3 + 1], iK[1 * 3 + c2]));
      s = __fadd_rn(s, __fmul_rn(R[r * 3 + 2], iK[2 * 3 + c2]));
      o[12 + r * 3 + c2] = s;
    }
  for (int k = 0; k < 3; ++k) o[21 + k] = ldin(trans, (size_t)i * 3 + k, fp32m);
}

__global__ void zero_kernel(float4* __restrict__ acc, int n4) {
  int i = blockIdx.x * blockDim.x + threadIdx.x;
  if (i < n4) acc[i] = make_float4(0.f, 0.f, 0.f, 0.f);
}

// One wave per point; lane = channel. Strict fp32, numpy op order throughout.
__global__ __launch_bounds__(256) void scatter_kernel(
    const void* __restrict__ x, const float* __restrict__ params,
    float* __restrict__ acc) {
  int tid = threadIdx.x;
  int c = tid & 63;
  int p = blockIdx.x * 4 + (tid >> 6);
  int w = p % FW;
  int t = p / FW;
  int h = t % FH;
  t /= FH;
  int d = t % D;
  t /= D;
  int n = t % N;
  int b = t / N;
  const float* pr = params + (b * N + n) * PARAMS_PER_CAM;
  int fp32m = ((const int*)params)[FLAG_IDX];
  // frustum: np.linspace in f64, cast f32; endpoint pinned exactly
  float u = (w == FW - 1) ? 703.0f : (float)((double)w * (703.0 / 43.0));
  float v = (float)(17 * h);    // linspace(0,255,16), exact
  float dep = (float)(2 + d);   // linspace(2,42,41), exact
  // pts = frustum - post_trans
  float ax = __fsub_rn(u, pr[9]);
  float ay = __fsub_rn(v, pr[10]);
  float az = __fsub_rn(dep, pr[11]);
  // einsum(inv(post_rots), pts) — strict left-fold
  float qx = __fadd_rn(__fadd_rn(__fmul_rn(pr[0], ax), __fmul_rn(pr[1], ay)),
                       __fmul_rn(pr[2], az));
  float qy = __fadd_rn(__fadd_rn(__fmul_rn(pr[3], ax), __fmul_rn(pr[4], ay)),
                       __fmul_rn(pr[5], az));
  float qz = __fadd_rn(__fadd_rn(__fmul_rn(pr[6], ax), __fmul_rn(pr[7], ay)),
                       __fmul_rn(pr[8], az));
  // undo perspective: (u*d, v*d, d)
  qx = __fmul_rn(qx, qz);
  qy = __fmul_rn(qy, qz);
  // einsum(combine, pts) + trans
  float gx = __fadd_rn(
      __fadd_rn(__fadd_rn(__fmul_rn(pr[12], qx), __fmul_rn(pr[13], qy)),
                __fmul_rn(pr[14], qz)),
      pr[21]);
  float gy = __fadd_rn(
      __fadd_rn(__fadd_rn(__fmul_rn(pr[15], qx), __fmul_rn(pr[16], qy)),
                __fmul_rn(pr[17], qz)),
      pr[22]);
  float gz = __fadd_rn(
      __fadd_rn(__fadd_rn(__fmul_rn(pr[18], qx), __fmul_rn(pr[19], qy)),
                __fmul_rn(pr[20], qz)),
      pr[23]);
  // ((geom - (BX - DX/2)) / DX).astype(int32): trunc toward zero
  int ix = (int)__fdiv_rn(__fsub_rn(gx, -50.0f), 0.5f);
  int iy = (int)__fdiv_rn(__fsub_rn(gy, -50.0f), 0.5f);
  int iz = (int)__fdiv_rn(__fsub_rn(gz, -10.0f), 20.0f);
  if (ix >= 0 && ix < NX && iy >= 0 && iy < NY && iz == 0) {
    float val = ldin(x, (size_t)p * C + c, fp32m);
    size_t vox = ((size_t)(b * NY + iy) * NX + ix) * (size_t)C + c;
    atomicAdd(acc + vox, val);
  }
}

// (B,NY,NX,C) fp32 -> (B,C,NY,NX) output dtype; LDS-tiled transpose.
__global__ __launch_bounds__(256) void finalize_kernel(
    const float* __restrict__ acc, void* __restrict__ out,
    const float* __restrict__ params) {
  int fp32m = ((const int*)params)[FLAG_IDX];
  int blk = blockIdx.x;
  int x0 = (blk % 5) * 40;
  int y = (blk / 5) % NY;
  int b = blk / (5 * NY);
  __shared__ float tile[40][C + 1];
  const float* src = acc + ((size_t)(b * NY + y) * NX + x0) * (size_t)C;
  for (int i = threadIdx.x; i < 40 * C; i += 256)
    tile[i >> 6][i & 63] = src[i];
  __syncthreads();
  for (int i = threadIdx.x; i < 40 * C; i += 256) {
    int xx = i % 40;
    int cc = i / 40;
    size_t o = ((size_t)(b * C + cc) * NY + y) * NX + x0 + xx;
    float vv = tile[xx][cc];
    if (fp32m)
      ((float*)out)[o] = vv;
    else
      ((__hip_bfloat16*)out)[o] = __float2bfloat16(vv);
  }
}

extern "C" void kernel_launch(void* const* d_in, const int* in_sizes, int n_in,
                              void* d_out, int out_size, void* d_ws,
                              size_t ws_size, hipStream_t stream) {
  const void* x = d_in[0];
  const void* rots = d_in[1];
  const void* trans = d_in[2];
  const void* intr = d_in[3];
  const void* prots = d_in[4];
  const void* ptrans = d_in[5];

  float* acc = (float*)d_ws;        // 10.24M fp32 accumulator
  float* params = acc + ACC_ELEMS;  // 576 fp32 + 1 int flag

  setup_kernel<<<1, 64, 0, stream>>>(rots, trans, intr, prots, ptrans, params);

  int n4 = (int)(ACC_ELEMS / 4);
  zero_kernel<<<(n4 + 255) / 256, 256, 0, stream>>>((float4*)acc, n4);

  scatter_kernel<<<NPRIME / 4, 256, 0, stream>>>(x, params, acc);

  finalize_kernel<<<B * NY * 5, 256, 0, stream>>>(acc, d_out, params);
}

// Round 3
// 319.688 us; speedup vs baseline: 1.4565x; 1.4565x over previous
//
#include <hip/hip_runtime.h>
#include <hip/hip_bf16.h>

namespace {
constexpr int B = 4, N = 6, D = 41, FH = 16, FW = 44, C = 64;
constexpr int NX = 200, NY = 200;                 // NZ = 1
constexpr int NGROUPS = B * N * D * FW;           // 43296 ray-groups (all h)
constexpr long long ACC_ELEMS = (long long)B * NY * NX * C;  // 10,240,000
constexpr int PARAMS_PER_CAM = 24;                // iPR[9], pt[3], M[9], t[3]
constexpr int FLAG_IDX = B * N * PARAMS_PER_CAM;  // int flag at params[576]
}

// Load input element as fp32, whatever the storage dtype actually is.
__device__ __forceinline__ float ldin(const void* p, size_t idx, int fp32m) {
  return fp32m ? ((const float*)p)[idx]
               : __bfloat162float(((const __hip_bfloat16*)p)[idx]);
}

// Strict fp32 left-fold 3-term dot (numpy einsum order, no FMA).
__device__ __forceinline__ float dot3(float m0, float m1, float m2, float a0,
                                      float a1, float a2) {
  return __fadd_rn(__fadd_rn(__fmul_rn(m0, a0), __fmul_rn(m1, a1)),
                   __fmul_rn(m2, a2));
}

// f64 adjugate inverse -> f32 (used for post_rots; exact for identity).
__device__ inline void inv3x3_f64(const float a_[9], float o[9]) {
  double a[9];
  for (int k = 0; k < 9; ++k) a[k] = (double)a_[k];
  double c00 = a[4] * a[8] - a[5] * a[7];
  double c01 = a[5] * a[6] - a[3] * a[8];
  double c02 = a[3] * a[7] - a[4] * a[6];
  double det = a[0] * c00 + a[1] * c01 + a[2] * c02;
  double id = 1.0 / det;
  o[0] = (float)(c00 * id);
  o[1] = (float)((a[2] * a[7] - a[1] * a[8]) * id);
  o[2] = (float)((a[1] * a[5] - a[2] * a[4]) * id);
  o[3] = (float)(c01 * id);
  o[4] = (float)((a[0] * a[8] - a[2] * a[6]) * id);
  o[5] = (float)((a[2] * a[3] - a[0] * a[5]) * id);
  o[6] = (float)(c02 * id);
  o[7] = (float)((a[1] * a[6] - a[0] * a[7]) * id);
  o[8] = (float)((a[0] * a[4] - a[1] * a[3]) * id);
}

// One thread per (b,n). Builds iPR, post_trans, combine = rots @ inv(intrins),
// trans — replicating numpy fp32 semantics (LAPACK strti2 for the upper-
// triangular intrinsics; strict no-FMA fp32 matmul).
__global__ void setup_kernel(const void* rots, const void* trans,
                             const void* intr, const void* prots,
                             const void* ptrans, float* params) {
  int i = threadIdx.x;
  float probe = ((const float*)intr)[0];  // 500.0 if fp32; denormal if bf16
  int fp32m = (probe > 100.f && probe < 2000.f) ? 1 : 0;
  if (i == 0) ((int*)params)[FLAG_IDX] = fp32m;
  if (i >= B * N) return;
  float R[9], K[9], PR[9];
  for (int k = 0; k < 9; ++k) {
    R[k] = ldin(rots, (size_t)i * 9 + k, fp32m);
    K[k] = ldin(intr, (size_t)i * 9 + k, fp32m);
    PR[k] = ldin(prots, (size_t)i * 9 + k, fp32m);
  }
  float iPR[9];
  inv3x3_f64(PR, iPR);  // exact identity for this problem
  // LAPACK strti2 (upper, non-unit) on K = [[fx,0,cx],[0,fy,cy],[0,0,1]]
  float i00 = __fdiv_rn(1.f, K[0]);
  float i11 = __fdiv_rn(1.f, K[4]);
  float i22 = __fdiv_rn(1.f, K[8]);
  float i01 = __fmul_rn(-i11, __fmul_rn(i00, K[1]));  // K[1]=0 -> 0
  float x1 = __fmul_rn(i00, K[2]);
  x1 = __fadd_rn(x1, __fmul_rn(K[5], i01));
  float x2 = __fmul_rn(i11, K[5]);
  float i02 = __fmul_rn(-i22, x1);
  float i12 = __fmul_rn(-i22, x2);
  float iK[9] = {i00, i01, i02, 0.f, i11, i12, 0.f, 0.f, i22};
  float* o = params + i * PARAMS_PER_CAM;
  for (int k = 0; k < 9; ++k) o[k] = iPR[k];
  for (int k = 0; k < 3; ++k) o[9 + k] = ldin(ptrans, (size_t)i * 3 + k, fp32m);
  // combine = R @ iK, strict fp32 left-fold (numpy matmul order, no FMA)
  for (int r = 0; r < 3; ++r)
    for (int c2 = 0; c2 < 3; ++c2)
      o[12 + r * 3 + c2] = dot3(R[r * 3], R[r * 3 + 1], R[r * 3 + 2],
                                iK[c2], iK[3 + c2], iK[6 + c2]);
  for (int k = 0; k < 3; ++k) o[21 + k] = ldin(trans, (size_t)i * 3 + k, fp32m);
}

__global__ void zero_kernel(float4* __restrict__ acc, int n4) {
  int i = blockIdx.x * blockDim.x + threadIdx.x;
  if (i < n4) acc[i] = make_float4(0.f, 0.f, 0.f, 0.f);
}

// One wave per (b,n,d,w) ray-group; lane = channel. Loop over FH=16 image
// rows with run-merge: all h of a group land in the same BEV voxel (combine
// has exactly-zero v-coefficients for ego x,y), so consecutive h accumulate
// in registers and flush ONE atomicAdd per distinct voxel (~16x fewer
// atomics). Correctness does NOT depend on that analysis: the per-h voxel is
// computed with bit-identical fp32 ops, and any change of voxel flushes.
__global__ __launch_bounds__(256) void scatter_kernel(
    const void* __restrict__ x, const float* __restrict__ params,
    float* __restrict__ acc) {
  int tid = threadIdx.x;
  int c = tid & 63;
  int g = blockIdx.x * 4 + (tid >> 6);  // group over (b,n,d,w), w fastest
  int w = g % FW;
  int t = g / FW;
  int d = t % D;
  t /= D;
  int n = t % N;
  int b = t / N;
  const float* pr = params + (b * N + n) * PARAMS_PER_CAM;
  int fp32m = ((const int*)params)[FLAG_IDX];
  // frustum: np.linspace in f64, cast f32; endpoint pinned exactly
  float u = (w == FW - 1) ? 703.0f : (float)((double)w * (703.0 / 43.0));
  float dep = (float)(2 + d);  // linspace(2,42,41), exact
  float ax = __fsub_rn(u, pr[9]);
  float az = __fsub_rn(dep, pr[11]);
  const size_t hstride = (size_t)FW * C;  // 2816 elems
  const size_t base = ((((size_t)(b * N + n) * D + d) * FH) * FW + w) * C + c;
  float sum = 0.f;
  int curvox = -1;
  for (int h = 0; h < FH; ++h) {
    float v = (float)(17 * h);  // linspace(0,255,16), exact
    float ay = __fsub_rn(v, pr[10]);
    // einsum(inv(post_rots), pts)
    float qx = dot3(pr[0], pr[1], pr[2], ax, ay, az);
    float qy = dot3(pr[3], pr[4], pr[5], ax, ay, az);
    float qz = dot3(pr[6], pr[7], pr[8], ax, ay, az);
    // undo perspective
    qx = __fmul_rn(qx, qz);
    qy = __fmul_rn(qy, qz);
    // einsum(combine, pts) + trans
    float gx = __fadd_rn(dot3(pr[12], pr[13], pr[14], qx, qy, qz), pr[21]);
    float gy = __fadd_rn(dot3(pr[15], pr[16], pr[17], qx, qy, qz), pr[22]);
    float gz = __fadd_rn(dot3(pr[18], pr[19], pr[20], qx, qy, qz), pr[23]);
    // ((geom - (BX - DX/2)) / DX).astype(int32): trunc toward zero
    int ix = (int)__fdiv_rn(__fsub_rn(gx, -50.0f), 0.5f);
    int iy = (int)__fdiv_rn(__fsub_rn(gy, -50.0f), 0.5f);
    int iz = (int)__fdiv_rn(__fsub_rn(gz, -10.0f), 20.0f);
    if (ix >= 0 && ix < NX && iy >= 0 && iy < NY && iz == 0) {
      int vox = (b * NY + iy) * NX + ix;
      if (vox != curvox) {
        if (curvox >= 0)
          atomicAdd(acc + (size_t)curvox * C + c, sum);
        sum = 0.f;
        curvox = vox;
      }
      sum = __fadd_rn(sum, ldin(x, base + (size_t)h * hstride, fp32m));
    }
  }
  if (curvox >= 0) atomicAdd(acc + (size_t)curvox * C + c, sum);
}

// (B,NY,NX,C) fp32 -> (B,C,NY,NX) out dtype. One block per (b,y) row:
// coalesced float4 reads of the 50 KB acc row -> LDS (pad 65) -> coalesced
// float4 writes, one 800 B row per channel.
__global__ __launch_bounds__(256) void finalize_kernel(
    const float* __restrict__ acc, void* __restrict__ out,
    const float* __restrict__ params) {
  int fp32m = ((const int*)params)[FLAG_IDX];
  int y = blockIdx.x % NY;
  int b = blockIdx.x / NY;
  __shared__ float tile[NX * 65];  // [x][c], pad 64->65
  const float4* src = (const float4*)(acc + (size_t)(b * NY + y) * NX * C);
  for (int i = threadIdx.x; i < NX * 16; i += 256) {  // 3200 float4
    float4 vv = src[i];
    int xx = i >> 4, c4 = i & 15;
    float* dst = &tile[xx * 65 + c4 * 4];
    dst[0] = vv.x;
    dst[1] = vv.y;
    dst[2] = vv.z;
    dst[3] = vv.w;
  }
  __syncthreads();
  for (int i = threadIdx.x; i < C * (NX / 4); i += 256) {  // 64*50 = 3200
    int cc = i / (NX / 4), k = i % (NX / 4);
    int xx = 4 * k;
    float4 vv;
    vv.x = tile[xx * 65 + cc];
    vv.y = tile[(xx + 1) * 65 + cc];
    vv.z = tile[(xx + 2) * 65 + cc];
    vv.w = tile[(xx + 3) * 65 + cc];
    size_t o = ((size_t)(b * C + cc) * NY + y) * NX + xx;
    if (fp32m) {
      *(float4*)((float*)out + o) = vv;
    } else {
      __hip_bfloat16* op = (__hip_bfloat16*)out + o;
      op[0] = __float2bfloat16(vv.x);
      op[1] = __float2bfloat16(vv.y);
      op[2] = __float2bfloat16(vv.z);
      op[3] = __float2bfloat16(vv.w);
    }
  }
}

extern "C" void kernel_launch(void* const* d_in, const int* in_sizes, int n_in,
                              void* d_out, int out_size, void* d_ws,
                              size_t ws_size, hipStream_t stream) {
  const void* x = d_in[0];
  const void* rots = d_in[1];
  const void* trans = d_in[2];
  const void* intr = d_in[3];
  const void* prots = d_in[4];
  const void* ptrans = d_in[5];

  float* acc = (float*)d_ws;        // 10.24M fp32 accumulator
  float* params = acc + ACC_ELEMS;  // 576 fp32 + 1 int flag

  setup_kernel<<<1, 64, 0, stream>>>(rots, trans, intr, prots, ptrans, params);

  int n4 = (int)(ACC_ELEMS / 4);
  zero_kernel<<<(n4 + 255) / 256, 256, 0, stream>>>((float4*)acc, n4);

  scatter_kernel<<<NGROUPS / 4, 256, 0, stream>>>(x, params, acc);

  finalize_kernel<<<B * NY, 256, 0, stream>>>(acc, d_out, params);
}